// Round 9
// baseline (166.731 us; speedup 1.0000x reference)
//
#include <hip/hip_runtime.h>
#include <hip/hip_bf16.h>
#include <math.h>

typedef __bf16 bf16;
typedef __bf16 bf16x2 __attribute__((ext_vector_type(2)));
typedef __bf16 bf16x4 __attribute__((ext_vector_type(4)));
typedef __bf16 bf16x8 __attribute__((ext_vector_type(8)));
typedef float f32x2 __attribute__((ext_vector_type(2)));
typedef float f32x4 __attribute__((ext_vector_type(4)));
typedef float f32x16 __attribute__((ext_vector_type(16)));
typedef int i32x2 __attribute__((ext_vector_type(2)));
typedef int i32x4 __attribute__((ext_vector_type(4)));

#define MFMA16(a, b, c) __builtin_amdgcn_mfma_f32_16x16x32_bf16(a, b, c, 0, 0, 0)
#define MFMA32(a, b, c) __builtin_amdgcn_mfma_f32_32x32x16_bf16(a, b, c, 0, 0, 0)

constexpr int D_MODEL = 1024;
constexpr int N_QKV   = 3072;
constexpr int BATCH   = 2;
constexpr int SEQ     = 2048;
constexpr int NH      = 16;
constexpr int DH      = 64;
constexpr int M_TOT   = BATCH * SEQ;   // 4096

__device__ __forceinline__ void gl_lds16(const bf16* g, bf16* l) {
    __builtin_amdgcn_global_load_lds(
        (const __attribute__((address_space(1))) void*)g,
        (__attribute__((address_space(3))) void*)l, 16, 0, 0);
}

__device__ __forceinline__ void pl32swap(int& a, int& b) {
    i32x2 r = __builtin_amdgcn_permlane32_swap(a, b, false, false);
    a = r[0];
    b = r[1];
}

template <int N> __device__ __forceinline__ void waitv() {
    asm volatile("s_waitcnt vmcnt(%0)" :: "n"(N) : "memory");
}
__device__ __forceinline__ void waitlgkm0() {
    asm volatile("s_waitcnt lgkmcnt(0)" ::: "memory");
}

// ---------------------------------------------------------------------------
// Merged pre-pass (unchanged).
// ---------------------------------------------------------------------------
__device__ __forceinline__ void transpose_tile(
    const float* __restrict__ in, bf16* __restrict__ out,
    int K, int N, int n0, int k0, bf16 (*T)[72], bool permute)
{
    const int tid = threadIdx.x;
    const int r   = tid >> 2;
    const int c4  = (tid & 3) * 16;

    const float* src = in + (size_t)(k0 + r) * N + n0 + c4;
    f32x4 v0 = *(const f32x4*)(src + 0);
    f32x4 v1 = *(const f32x4*)(src + 4);
    f32x4 v2 = *(const f32x4*)(src + 8);
    f32x4 v3 = *(const f32x4*)(src + 12);
    #pragma unroll
    for (int j = 0; j < 4; j++) {
        T[c4 + j][r]      = (bf16)v0[j];
        T[c4 + 4 + j][r]  = (bf16)v1[j];
        T[c4 + 8 + j][r]  = (bf16)v2[j];
        T[c4 + 12 + j][r] = (bf16)v3[j];
    }
    __syncthreads();
    int rowg = n0 + r;
    if (permute) {
        const int which = rowg % 3;
        const int h     = rowg / 192;
        const int d     = (rowg % 192) / 3;
        rowg = which * 1024 + h * 64 + d;
    }
    bf16* dst = out + (size_t)rowg * K + k0 + c4;
    *(bf16x8*)(dst)     = *(const bf16x8*)&T[r][c4];
    *(bf16x8*)(dst + 8) = *(const bf16x8*)&T[r][c4 + 8];
}

__global__ __launch_bounds__(256) void prepass_kernel(
    const float* __restrict__ X, const float* __restrict__ Wqkv,
    const float* __restrict__ Wout,
    bf16* __restrict__ xb, bf16* __restrict__ wqkv_t, bf16* __restrict__ wout_t)
{
    __shared__ bf16 T[64][72];
    const int b = blockIdx.x;
    if (b < 2048) {
        const size_t i = ((size_t)b * 256 + threadIdx.x) * 8;
        f32x4 a0 = *(const f32x4*)(X + i);
        f32x4 a1 = *(const f32x4*)(X + i + 4);
        bf16x8 w;
        #pragma unroll
        for (int j = 0; j < 4; j++) { w[j] = (bf16)a0[j]; w[j + 4] = (bf16)a1[j]; }
        *(bf16x8*)(xb + i) = w;
    } else if (b < 2048 + 768) {
        const int idx = b - 2048;                 // 48 x 16
        transpose_tile(Wqkv, wqkv_t, D_MODEL, N_QKV,
                       (idx % 48) * 64, (idx / 48) * 64, T, true);
    } else {
        const int idx = b - 2816;                 // 16 x 16
        transpose_tile(Wout, wout_t, D_MODEL, D_MODEL,
                       (idx % 16) * 64, (idx / 16) * 64, T, false);
    }
}

// ---------------------------------------------------------------------------
// Kernel 1: qkv = Xb @ Wt^T — 256x256 tile, ring-of-4, ping-pong frag banks,
// one barrier per phase, counted vmcnt (unchanged from R5).
// ---------------------------------------------------------------------------
__global__ __launch_bounds__(512, 2) void qkv_gemm_kernel(
    const bf16* __restrict__ Xb, const bf16* __restrict__ Wt,
    bf16* __restrict__ qb, bf16* __restrict__ kb, bf16* __restrict__ vb)
{
    __shared__ __align__(16) bf16 smem[65536];   // 128 KB: A slabs | B slabs
    bf16* const sA = smem;                        // 4 x 8192 elems
    bf16* const sB = smem + 32768;                // 4 x 8192 elems

    const int tid  = threadIdx.x;
    const int wave = tid >> 6;
    const int lane = tid & 63;
    const int quad = lane >> 4;
    const int l16  = lane & 15;
    const int wr   = wave >> 2;        // 0..1 : A row half
    const int wc   = wave & 3;         // 0..3 : B col quarter
    const int m0   = blockIdx.x * 256;
    const int n0   = blockIdx.y * 256;

    const int sr2  = tid >> 3;                   // super-row 0..63
    const int c8p  = (tid & 7) ^ (sr2 & 7);      // source chunk-in-superrow
    const int stR0 = (sr2 << 1) | (c8p >> 2);    // global row 0..127
    const int stC0 = (c8p & 3) << 3;             // source k-col offset

    const bf16* Asrc = Xb + (size_t)(m0 + stR0) * D_MODEL + stC0;
    const bf16* Bsrc = Wt + (size_t)(n0 + stR0) * D_MODEL + stC0;

#define STG(s, kbo)                                                          \
    do {                                                                     \
        gl_lds16(Asrc + (kbo),                 sA + (s) * 8192 + tid * 8);   \
        gl_lds16(Asrc + 128 * D_MODEL + (kbo), sA + (s) * 8192 + 4096 + tid * 8); \
        gl_lds16(Bsrc + (kbo),                 sB + (s) * 8192 + tid * 8);   \
        gl_lds16(Bsrc + 128 * D_MODEL + (kbo), sB + (s) * 8192 + 4096 + tid * 8); \
    } while (0)

    const int foff = ((l16 >> 1) << 6) +
                     (((((l16 & 1) << 2) | quad) ^ ((l16 >> 1) & 7)) << 3);

    f32x4 acc[8][4];
    #pragma unroll
    for (int a = 0; a < 8; a++)
        #pragma unroll
        for (int b = 0; b < 4; b++) acc[a][b] = {0.f, 0.f, 0.f, 0.f};

    bf16x8 afA[8], bfA[4], afB[8], bfB[4];

    // prologue: stage ksteps 0..2; certify 0,1 landed; read kstep 0 -> bank A
    STG(0, 0); STG(1, 32); STG(2, 64);
    waitv<4>();
    __builtin_amdgcn_s_barrier();
    {
        const bf16* A0 = sA + wr * 4096;
        const bf16* B0 = sB + wc * 2048;
        #pragma unroll
        for (int mi = 0; mi < 8; mi++)
            afA[mi] = *(const bf16x8*)&A0[mi * 512 + foff];
        #pragma unroll
        for (int ni = 0; ni < 4; ni++)
            bfA[ni] = *(const bf16x8*)&B0[ni * 512 + foff];
    }

    int p = 0;

#define PHASE(CA, CB, NA, NB, DOSTG, DONXT, WV)                              \
    {                                                                        \
        if (DOSTG) { const int kst = p + 3; STG((kst & 3), kst * 32); }      \
        const int sn = (p + 1) & 3;                                          \
        const bf16* An_ = sA + sn * 8192 + wr * 4096;                        \
        const bf16* Bn_ = sB + sn * 8192 + wc * 2048;                        \
        __builtin_amdgcn_s_setprio(1);                                       \
        _Pragma("unroll") for (int c = 0; c < 4; c++) {                      \
            _Pragma("unroll") for (int m2 = 0; m2 < 2; m2++)                 \
                _Pragma("unroll") for (int ni = 0; ni < 4; ni++)             \
                    acc[c * 2 + m2][ni] =                                    \
                        MFMA16(CA[c * 2 + m2], CB[ni], acc[c * 2 + m2][ni]); \
            if (DONXT) {                                                     \
                NA[c * 2]     = *(const bf16x8*)&An_[(c * 2) * 512 + foff];  \
                NA[c * 2 + 1] = *(const bf16x8*)&An_[(c * 2 + 1) * 512 + foff]; \
            }                                                                \
        }                                                                    \
        if (DONXT) {                                                         \
            _Pragma("unroll") for (int ni = 0; ni < 4; ni++)                 \
                NB[ni] = *(const bf16x8*)&Bn_[ni * 512 + foff];              \
        }                                                                    \
        __builtin_amdgcn_s_setprio(0);                                       \
        waitv<WV>();                                                         \
        __builtin_amdgcn_s_barrier();                                        \
        ++p;                                                                 \
    }

    for (int t = 0; t < 14; ++t) {
        PHASE(afA, bfA, afB, bfB, true, true, 4)     // p even
        PHASE(afB, bfB, afA, bfA, true, true, 4)     // p odd
    }
    PHASE(afA, bfA, afB, bfB, true,  true,  4)       // p=28 (stages kstep 31)
    PHASE(afB, bfB, afA, bfA, false, true,  0)       // p=29
    PHASE(afA, bfA, afB, bfB, false, true,  0)       // p=30
    PHASE(afB, bfB, afA, bfA, false, false, 0)       // p=31

#undef PHASE
#undef STG

    const int bb     = m0 >> 11;            // batch (uniform per wg)
    const int s_base = m0 & (SEQ - 1);

    if (n0 < 2048) {
        bf16* dst0 = (n0 < 1024) ? qb : kb;
        const int h = ((n0 + wc * 64) >> 6) & 15;
        const size_t bh = (size_t)(bb * NH + h);
        #pragma unroll
        for (int mi = 0; mi < 8; mi++) {
            const int s0 = s_base + wr * 128 + mi * 16 + quad * 4;
            #pragma unroll
            for (int ni = 0; ni < 4; ni++) {
                const int d = ni * 16 + l16;
                #pragma unroll
                for (int i = 0; i < 4; i++)
                    dst0[(bh * SEQ + s0 + i) * DH + d] = (bf16)acc[mi][ni][i];
            }
        }
    } else {
        __syncthreads();
        bf16* T = smem;                      // [256][256] bf16 = 128 KB
        #pragma unroll
        for (int ni = 0; ni < 4; ni++) {
            const int nl = wc * 64 + ni * 16 + l16;        // 0..255
            #pragma unroll
            for (int mi = 0; mi < 8; mi++) {
                const int ml = wr * 128 + mi * 16 + quad * 4;
                bf16x4 pv;
                #pragma unroll
                for (int i = 0; i < 4; i++) pv[i] = (bf16)acc[mi][ni][i];
                const int c   = ml >> 3;                    // 0..31
                const int swz = (c & 24) | ((c ^ nl) & 7);
                *(bf16x4*)&T[nl * 256 + swz * 8 + (ml & 7)] = pv;
            }
        }
        __syncthreads();
        const int hbase = (n0 - 2048) >> 6;
        #pragma unroll
        for (int it = 0; it < 8; it++) {
            const int nl = (tid >> 4) + it * 32;            // 0..255
            const int h  = hbase + (nl >> 6);
            const int d  = nl & 63;
            const size_t obase = ((size_t)(bb * NH + h) * DH + d) * SEQ + s_base;
            #pragma unroll
            for (int cc = 0; cc < 2; cc++) {
                const int c   = (tid & 15) + cc * 16;       // m-chunk 0..31
                const int swz = (c & 24) | ((c ^ nl) & 7);
                bf16x8 vv = *(const bf16x8*)&T[nl * 256 + swz * 8];
                *(bf16x8*)(vb + obase + c * 8) = vv;
            }
        }
    }
}

// ---------------------------------------------------------------------------
// Kernel 2: flash attention — exact R5-proven structure (64-key tiles, dbuf,
// single scalar l_acc; R7's zerov/pk-add trims reverted: −10% regression).
// ONE change vs R5: the K/V LDS swizzle gains the row's bits 3-4:
//   slot = chunk ^ (row&7) ^ ((row>>3)&3)
// applied consistently to staging source (pre-swizzle) and reads, so rows
// {r, r+8, r+16, r+24} — which a b128 read touches through lanes l32, l32+8,
// l32+16, l32+24 — land in 4 distinct 16B slots instead of 1 (bank-conflict
// fix targeting the constant 4.26M SQ_LDS_BANK_CONFLICT).
// ---------------------------------------------------------------------------
__global__ __launch_bounds__(512, 4) void attn_kernel(
    const bf16* __restrict__ qb, const bf16* __restrict__ kb,
    const bf16* __restrict__ vb, bf16* __restrict__ ob)
{
    __shared__ __align__(16) bf16 smem[32768];   // 64 KB

    const int tid  = threadIdx.x;
    const int wave = tid >> 6;
    const int grp  = wave >> 2;        // key half
    const int wq   = wave & 3;         // q sub-block
    const int lane = tid & 63;
    const int l32  = lane & 31;
    const int hi   = lane >> 5;
    const int ltid = tid & 255;
    const int bh   = blockIdx.x;
    const int q0   = blockIdx.y * 128;
    const size_t base  = (size_t)bh * SEQ * DH;
    const int    kbase = grp * (SEQ / 2);

    bf16* const KsB = smem + grp * 2 * 4096;
    bf16* const VtB = smem + 16384 + grp * 2 * 4096;

    constexpr float QSCALE = 0.125f * 1.44269504f;

    bf16x8 qf[4];
    {
        const size_t qoff = base + (size_t)(q0 + wq * 32 + l32) * DH + hi * 8;
        #pragma unroll
        for (int kc = 0; kc < 4; kc++) {
            qf[kc] = *(const bf16x8*)(qb + qoff + kc * 16);
            #pragma unroll
            for (int j = 0; j < 8; j++)
                qf[kc][j] = (bf16)((float)qf[kc][j] * QSCALE);
        }
    }

    f32x16 o_acc[2];
    #pragma unroll
    for (int i = 0; i < 16; i++) { o_acc[0][i] = 0.f; o_acc[1][i] = 0.f; }
    float l_acc = 0.f;

    // row-swizzle term for this lane's reads: (row&7) ^ ((row>>3)&3),
    // identical for both kblk halves and both K/V tiles (row = k*32 + l32).
    const int swz = (l32 & 7) ^ (l32 >> 3);

    const int so0 = ltid;
    const int so1 = 256 + ltid;
    const int sr0 = so0 >> 3, sc0 = ((so0 & 7) ^ (sr0 & 7) ^ ((sr0 >> 3) & 3)) * 8;
    const int sr1 = so1 >> 3, sc1 = ((so1 & 7) ^ (sr1 & 7) ^ ((sr1 >> 3) & 3)) * 8;

    #define STAGE(bufi, kk0)                                                   \
        do {                                                                   \
            gl_lds16(kb + base + (size_t)(kbase + (kk0) + sr0) * DH + sc0,     \
                     KsB + (bufi) * 4096 + so0 * 8);                           \
            gl_lds16(kb + base + (size_t)(kbase + (kk0) + sr1) * DH + sc1,     \
                     KsB + (bufi) * 4096 + so1 * 8);                           \
            gl_lds16(vb + base + (size_t)sr0 * SEQ + kbase + (kk0) + sc0,      \
                     VtB + (bufi) * 4096 + so0 * 8);                           \
            gl_lds16(vb + base + (size_t)sr1 * SEQ + kbase + (kk0) + sc1,      \
                     VtB + (bufi) * 4096 + so1 * 8);                           \
        } while (0)

    STAGE(0, 0);
    int buf = 0;

    for (int kt = 0; kt < SEQ / 128; ++kt) {
        __syncthreads();
        if (kt + 1 < SEQ / 128) STAGE(buf ^ 1, (kt + 1) * 64);

        const bf16* Kst = KsB + buf * 4096;
        const bf16* Vtt = VtB + buf * 4096;

        #pragma unroll
        for (int kblk = 0; kblk < 2; kblk++) {
            f32x16 sacc;
            #pragma unroll
            for (int i = 0; i < 16; i++) sacc[i] = 0.f;
            #pragma unroll
            for (int kc = 0; kc < 4; kc++) {
                const int cko = ((2 * kc + hi) ^ swz) * 8;
                bf16x8 kf = *(const bf16x8*)
                    &Kst[(kblk * 32 + l32) * 64 + cko];
                sacc = MFMA32(kf, qf[kc], sacc);
            }

            int w[8];
            #pragma unroll
            for (int c = 0; c < 8; c++) {
                const float e0 = __builtin_amdgcn_exp2f(sacc[2 * c]);
                const float e1 = __builtin_amdgcn_exp2f(sacc[2 * c + 1]);
                l_acc += e0;
                l_acc += e1;
                bf16x2 t; t[0] = (bf16)e0; t[1] = (bf16)e1;
                w[c] = __builtin_bit_cast(int, t);
            }
            #pragma unroll
            for (int cc = 0; cc < 2; cc++) {
                pl32swap(w[cc * 4 + 0], w[cc * 4 + 2]);
                pl32swap(w[cc * 4 + 1], w[cc * 4 + 3]);
                i32x4 fi = {w[cc * 4 + 0], w[cc * 4 + 1],
                            w[cc * 4 + 2], w[cc * 4 + 3]};
                bf16x8 pa = __builtin_bit_cast(bf16x8, fi);

                const int kc = kblk * 2 + cc;
                const int cko = ((2 * kc + hi) ^ swz) * 8;
                #pragma unroll
                for (int nb = 0; nb < 2; nb++) {
                    bf16x8 vf = *(const bf16x8*)
                        &Vtt[(nb * 32 + l32) * 64 + cko];
                    o_acc[nb] = MFMA32(pa, vf, o_acc[nb]);
                }
            }
        }
        buf ^= 1;
    }
    #undef STAGE

    const float l_q = l_acc + __shfl_xor(l_acc, 32);

    float* cO  = (float*)smem;            // [4][64][32] f32, swizzled
    float* cL1 = (float*)smem + 8192;     // [4][32] : grp1 partial l
    float* cL2 = (float*)smem + 8320;     // [4][32] : total l

    __syncthreads();                      // everyone done with Ks/Vt
    if (grp == 1) {
        #pragma unroll
        for (int nb = 0; nb < 2; nb++)
            #pragma unroll
            for (int c4 = 0; c4 < 4; c4++) {
                const int j = nb * 4 + c4;
                f32x4 v = { o_acc[nb][c4 * 4 + 0], o_acc[nb][c4 * 4 + 1],
                            o_acc[nb][c4 * 4 + 2], o_acc[nb][c4 * 4 + 3] };
                *(f32x4*)&cO[(wq * 64 + lane) * 32 + ((j ^ (lane & 7)) * 4)] = v;
            }
        if (hi == 0) cL1[wq * 32 + l32] = l_q;
    }
    __syncthreads();
    if (grp == 0) {
        #pragma unroll
        for (int nb = 0; nb < 2; nb++)
            #pragma unroll
            for (int c4 = 0; c4 < 4; c4++) {
                const int j = nb * 4 + c4;
                f32x4 v = *(const f32x4*)
                    &cO[(wq * 64 + lane) * 32 + ((j ^ (lane & 7)) * 4)];
                #pragma unroll
                for (int e = 0; e < 4; e++) o_acc[nb][c4 * 4 + e] += v[e];
            }
        if (hi == 0) cL2[wq * 32 + l32] = l_q + cL1[wq * 32 + l32];
    }
    __syncthreads();
    if (grp == 0) {
        const int b = bh >> 4, h = bh & 15;
        #pragma unroll
        for (int i = 0; i < 16; i++) {
            const int qrow = (i & 3) + 8 * (i >> 2) + 4 * hi;
            const int q = q0 + wq * 32 + qrow;
            const float li = 1.0f / cL2[wq * 32 + qrow];
            #pragma unroll
            for (int nb = 0; nb < 2; nb++)
                ob[((size_t)(b * SEQ + q) * NH + h) * DH + nb * 32 + l32] =
                    (bf16)(o_acc[nb][i] * li);
        }
    }
}

// ---------------------------------------------------------------------------
// Kernel 3: out = attn @ Wout^T — pipelined 128x128 (unchanged from R4).
// ---------------------------------------------------------------------------
__global__ __launch_bounds__(256, 2) void out_gemm_kernel(
    const bf16* __restrict__ A, const bf16* __restrict__ Wt,
    float* __restrict__ out)
{
    __shared__ __align__(16) bf16 smem[32768];   // 64 KB
    bf16* const sA = smem;                        // 4 x 4096 elems
    bf16* const sB = smem + 16384;                // 4 x 4096 elems

    const int tid  = threadIdx.x;
    const int wave = tid >> 6;
    const int lane = tid & 63;
    const int quad = lane >> 4;
    const int l16  = lane & 15;
    const int wr   = wave >> 1;        // 0..1 : A row half
    const int wc   = wave & 1;         // 0..1 : B col half
    const int m0   = blockIdx.x * 128;
    const int n0   = blockIdx.y * 128;

    const int sr2  = tid >> 3;                   // super-row 0..31
    const int c8p  = (tid & 7) ^ (sr2 & 7);
    const int stR0 = (sr2 << 1) | (c8p >> 2);    // row 0..63 (slot1: +64)
    const int stC0 = (c8p & 3) << 3;

    const bf16* Asrc = A  + (size_t)(m0 + stR0) * D_MODEL + stC0;
    const bf16* Bsrc = Wt + (size_t)(n0 + stR0) * D_MODEL + stC0;

#define STG(s, kbo)                                                          \
    do {                                                                     \
        gl_lds16(Asrc + (kbo),                sA + (s) * 4096 + tid * 8);    \
        gl_lds16(Asrc + 64 * D_MODEL + (kbo), sA + (s) * 4096 + 2048 + tid * 8); \
        gl_lds16(Bsrc + (kbo),                sB + (s) * 4096 + tid * 8);    \
        gl_lds16(Bsrc + 64 * D_MODEL + (kbo), sB + (s) * 4096 + 2048 + tid * 8); \
    } while (0)

    const int foff = ((l16 >> 1) << 6) +
                     (((((l16 & 1) << 2) | quad) ^ ((l16 >> 1) & 7)) << 3);

    f32x4 acc[4][4];
    #pragma unroll
    for (int a = 0; a < 4; a++)
        #pragma unroll
        for (int b = 0; b < 4; b++) acc[a][b] = {0.f, 0.f, 0.f, 0.f};

#define PHASE(s, jn, DOSTG, WV)                                              \
    {                                                                        \
        const bf16* Ab_ = sA + (s) * 4096 + wr * 2048;                       \
        const bf16* Bb_ = sB + (s) * 4096 + wc * 2048;                       \
        bf16x8 af[4], bfr[4];                                                \
        _Pragma("unroll") for (int mi = 0; mi < 4; mi++)                     \
            af[mi] = *(const bf16x8*)&Ab_[mi * 512 + foff];                  \
        _Pragma("unroll") for (int ni = 0; ni < 4; ni++)                     \
            bfr[ni] = *(const bf16x8*)&Bb_[ni * 512 + foff];                 \
        waitlgkm0();                                                         \
        __builtin_amdgcn_s_barrier();                                        \
        if (DOSTG) { STG((s), (jn) * 32); }                                  \
        __builtin_amdgcn_s_setprio(1);                                       \
        _Pragma("unroll") for (int mi = 0; mi < 4; mi++)                     \
            _Pragma("unroll") for (int ni = 0; ni < 4; ni++)                 \
                acc[mi][ni] = MFMA16(af[mi], bfr[ni], acc[mi][ni]);          \
        __builtin_amdgcn_s_setprio(0);                                       \
        waitv<WV>();                                                         \
        __builtin_amdgcn_s_barrier();                                        \
    }

    STG(0, 0); STG(1, 32); STG(2, 64); STG(3, 96);
    waitv<12>();
    __builtin_amdgcn_s_barrier();

    for (int t = 0; t < 7; ++t) {
        const int j = t * 4;
        PHASE(0, j + 4, true, 12)
        PHASE(1, j + 5, true, 12)
        PHASE(2, j + 6, true, 12)
        PHASE(3, j + 7, true, 12)
    }
    PHASE(0, 0, false, 8)
    PHASE(1, 0, false, 4)
    PHASE(2, 0, false, 0)
    PHASE(3, 0, false, 0)

#undef PHASE
#undef STG

    #pragma unroll
    for (int mi = 0; mi < 4; mi++) {
        const int row0 = m0 + wr * 64 + mi * 16 + quad * 4;
        #pragma unroll
        for (int ni = 0; ni < 4; ni++) {
            const int n = n0 + wc * 64 + ni * 16 + l16;
            #pragma unroll
            for (int i = 0; i < 4; i++)
                out[(size_t)(row0 + i) * D_MODEL + n] = acc[mi][ni][i];
        }
    }
}

// ---------------------------------------------------------------------------
extern "C" void kernel_launch(void* const* d_in, const int* in_sizes, int n_in,
                              void* d_out, int out_size, void* d_ws, size_t ws_size,
                              hipStream_t stream)
{
    const float* X    = (const float*)d_in[0];
    const float* Wqkv = (const float*)d_in[1];
    const float* Wout = (const float*)d_in[2];
    float* out        = (float*)d_out;

    const size_t n_elem = (size_t)M_TOT * D_MODEL;       // 4096*1024
    bf16* qb      = (bf16*)d_ws;
    bf16* kb      = qb + n_elem;
    bf16* vb      = kb + n_elem;
    bf16* attnb   = vb + n_elem;
    bf16* wqkv_t  = attnb + n_elem;                      // 3072*1024
    bf16* wout_t  = wqkv_t + (size_t)N_QKV * D_MODEL;    // 1024*1024
    bf16* xb      = wout_t + (size_t)D_MODEL * D_MODEL;  // 4096*1024

    prepass_kernel<<<3072, 256, 0, stream>>>(X, Wqkv, Wout, xb, wqkv_t, wout_t);

    qkv_gemm_kernel<<<dim3(M_TOT / 256, N_QKV / 256), 512, 0, stream>>>(
        xb, wqkv_t, qb, kb, vb);
    attn_kernel<<<dim3(BATCH * NH, SEQ / 128), 512, 0, stream>>>(qb, kb, vb, attnb);
    out_gemm_kernel<<<dim3(M_TOT / 128, D_MODEL / 128), 256, 0, stream>>>(
        attnb, wout_t, out);
}

// Round 10
// 160.429 us; speedup vs baseline: 1.0393x; 1.0393x over previous
//
#include <hip/hip_runtime.h>
#include <hip/hip_bf16.h>
#include <math.h>

typedef __bf16 bf16;
typedef __bf16 bf16x2 __attribute__((ext_vector_type(2)));
typedef __bf16 bf16x4 __attribute__((ext_vector_type(4)));
typedef __bf16 bf16x8 __attribute__((ext_vector_type(8)));
typedef float f32x2 __attribute__((ext_vector_type(2)));
typedef float f32x4 __attribute__((ext_vector_type(4)));
typedef float f32x16 __attribute__((ext_vector_type(16)));
typedef int i32x2 __attribute__((ext_vector_type(2)));
typedef int i32x4 __attribute__((ext_vector_type(4)));

#define MFMA16(a, b, c) __builtin_amdgcn_mfma_f32_16x16x32_bf16(a, b, c, 0, 0, 0)
#define MFMA32(a, b, c) __builtin_amdgcn_mfma_f32_32x32x16_bf16(a, b, c, 0, 0, 0)

constexpr int D_MODEL = 1024;
constexpr int N_QKV   = 3072;
constexpr int BATCH   = 2;
constexpr int SEQ     = 2048;
constexpr int NH      = 16;
constexpr int DH      = 64;
constexpr int M_TOT   = BATCH * SEQ;   // 4096

__device__ __forceinline__ void gl_lds16(const bf16* g, bf16* l) {
    __builtin_amdgcn_global_load_lds(
        (const __attribute__((address_space(1))) void*)g,
        (__attribute__((address_space(3))) void*)l, 16, 0, 0);
}

__device__ __forceinline__ void pl32swap(int& a, int& b) {
    i32x2 r = __builtin_amdgcn_permlane32_swap(a, b, false, false);
    a = r[0];
    b = r[1];
}

template <int N> __device__ __forceinline__ void waitv() {
    asm volatile("s_waitcnt vmcnt(%0)" :: "n"(N) : "memory");
}

// ---------------------------------------------------------------------------
// Merged pre-pass (unchanged).
// ---------------------------------------------------------------------------
__device__ __forceinline__ void transpose_tile(
    const float* __restrict__ in, bf16* __restrict__ out,
    int K, int N, int n0, int k0, bf16 (*T)[72], bool permute)
{
    const int tid = threadIdx.x;
    const int r   = tid >> 2;
    const int c4  = (tid & 3) * 16;

    const float* src = in + (size_t)(k0 + r) * N + n0 + c4;
    f32x4 v0 = *(const f32x4*)(src + 0);
    f32x4 v1 = *(const f32x4*)(src + 4);
    f32x4 v2 = *(const f32x4*)(src + 8);
    f32x4 v3 = *(const f32x4*)(src + 12);
    #pragma unroll
    for (int j = 0; j < 4; j++) {
        T[c4 + j][r]      = (bf16)v0[j];
        T[c4 + 4 + j][r]  = (bf16)v1[j];
        T[c4 + 8 + j][r]  = (bf16)v2[j];
        T[c4 + 12 + j][r] = (bf16)v3[j];
    }
    __syncthreads();
    int rowg = n0 + r;
    if (permute) {
        const int which = rowg % 3;
        const int h     = rowg / 192;
        const int d     = (rowg % 192) / 3;
        rowg = which * 1024 + h * 64 + d;
    }
    bf16* dst = out + (size_t)rowg * K + k0 + c4;
    *(bf16x8*)(dst)     = *(const bf16x8*)&T[r][c4];
    *(bf16x8*)(dst + 8) = *(const bf16x8*)&T[r][c4 + 8];
}

__global__ __launch_bounds__(256) void prepass_kernel(
    const float* __restrict__ X, const float* __restrict__ Wqkv,
    const float* __restrict__ Wout,
    bf16* __restrict__ xb, bf16* __restrict__ wqkv_t, bf16* __restrict__ wout_t)
{
    __shared__ bf16 T[64][72];
    const int b = blockIdx.x;
    if (b < 2048) {
        const size_t i = ((size_t)b * 256 + threadIdx.x) * 8;
        f32x4 a0 = *(const f32x4*)(X + i);
        f32x4 a1 = *(const f32x4*)(X + i + 4);
        bf16x8 w;
        #pragma unroll
        for (int j = 0; j < 4; j++) { w[j] = (bf16)a0[j]; w[j + 4] = (bf16)a1[j]; }
        *(bf16x8*)(xb + i) = w;
    } else if (b < 2048 + 768) {
        const int idx = b - 2048;                 // 48 x 16
        transpose_tile(Wqkv, wqkv_t, D_MODEL, N_QKV,
                       (idx % 48) * 64, (idx / 48) * 64, T, true);
    } else {
        const int idx = b - 2816;                 // 16 x 16
        transpose_tile(Wout, wout_t, D_MODEL, D_MODEL,
                       (idx % 16) * 64, (idx / 16) * 64, T, false);
    }
}

// ---------------------------------------------------------------------------
// Kernel 1: qkv = Xb @ Wt^T — 256x256 tile, ring-of-4, ping-pong frag banks,
// one barrier per phase, counted vmcnt (unchanged from R5).
// ---------------------------------------------------------------------------
__global__ __launch_bounds__(512, 2) void qkv_gemm_kernel(
    const bf16* __restrict__ Xb, const bf16* __restrict__ Wt,
    bf16* __restrict__ qb, bf16* __restrict__ kb, bf16* __restrict__ vb)
{
    __shared__ __align__(16) bf16 smem[65536];   // 128 KB: A slabs | B slabs
    bf16* const sA = smem;                        // 4 x 8192 elems
    bf16* const sB = smem + 32768;                // 4 x 8192 elems

    const int tid  = threadIdx.x;
    const int wave = tid >> 6;
    const int lane = tid & 63;
    const int quad = lane >> 4;
    const int l16  = lane & 15;
    const int wr   = wave >> 2;        // 0..1 : A row half
    const int wc   = wave & 3;         // 0..3 : B col quarter
    const int m0   = blockIdx.x * 256;
    const int n0   = blockIdx.y * 256;

    const int sr2  = tid >> 3;                   // super-row 0..63
    const int c8p  = (tid & 7) ^ (sr2 & 7);      // source chunk-in-superrow
    const int stR0 = (sr2 << 1) | (c8p >> 2);    // global row 0..127
    const int stC0 = (c8p & 3) << 3;             // source k-col offset

    const bf16* Asrc = Xb + (size_t)(m0 + stR0) * D_MODEL + stC0;
    const bf16* Bsrc = Wt + (size_t)(n0 + stR0) * D_MODEL + stC0;

#define STG(s, kbo)                                                          \
    do {                                                                     \
        gl_lds16(Asrc + (kbo),                 sA + (s) * 8192 + tid * 8);   \
        gl_lds16(Asrc + 128 * D_MODEL + (kbo), sA + (s) * 8192 + 4096 + tid * 8); \
        gl_lds16(Bsrc + (kbo),                 sB + (s) * 8192 + tid * 8);   \
        gl_lds16(Bsrc + 128 * D_MODEL + (kbo), sB + (s) * 8192 + 4096 + tid * 8); \
    } while (0)

    const int foff = ((l16 >> 1) << 6) +
                     (((((l16 & 1) << 2) | quad) ^ ((l16 >> 1) & 7)) << 3);

    f32x4 acc[8][4];
    #pragma unroll
    for (int a = 0; a < 8; a++)
        #pragma unroll
        for (int b = 0; b < 4; b++) acc[a][b] = {0.f, 0.f, 0.f, 0.f};

    bf16x8 afA[8], bfA[4], afB[8], bfB[4];

    // prologue: stage ksteps 0..2; certify 0,1 landed; read kstep 0 -> bank A
    STG(0, 0); STG(1, 32); STG(2, 64);
    waitv<4>();
    __builtin_amdgcn_s_barrier();
    {
        const bf16* A0 = sA + wr * 4096;
        const bf16* B0 = sB + wc * 2048;
        #pragma unroll
        for (int mi = 0; mi < 8; mi++)
            afA[mi] = *(const bf16x8*)&A0[mi * 512 + foff];
        #pragma unroll
        for (int ni = 0; ni < 4; ni++)
            bfA[ni] = *(const bf16x8*)&B0[ni * 512 + foff];
    }

    int p = 0;

#define PHASE(CA, CB, NA, NB, DOSTG, DONXT, WV)                              \
    {                                                                        \
        if (DOSTG) { const int kst = p + 3; STG((kst & 3), kst * 32); }      \
        const int sn = (p + 1) & 3;                                          \
        const bf16* An_ = sA + sn * 8192 + wr * 4096;                        \
        const bf16* Bn_ = sB + sn * 8192 + wc * 2048;                        \
        __builtin_amdgcn_s_setprio(1);                                       \
        _Pragma("unroll") for (int c = 0; c < 4; c++) {                      \
            _Pragma("unroll") for (int m2 = 0; m2 < 2; m2++)                 \
                _Pragma("unroll") for (int ni = 0; ni < 4; ni++)             \
                    acc[c * 2 + m2][ni] =                                    \
                        MFMA16(CA[c * 2 + m2], CB[ni], acc[c * 2 + m2][ni]); \
            if (DONXT) {                                                     \
                NA[c * 2]     = *(const bf16x8*)&An_[(c * 2) * 512 + foff];  \
                NA[c * 2 + 1] = *(const bf16x8*)&An_[(c * 2 + 1) * 512 + foff]; \
            }                                                                \
        }                                                                    \
        if (DONXT) {                                                         \
            _Pragma("unroll") for (int ni = 0; ni < 4; ni++)                 \
                NB[ni] = *(const bf16x8*)&Bn_[ni * 512 + foff];              \
        }                                                                    \
        __builtin_amdgcn_s_setprio(0);                                       \
        waitv<WV>();                                                         \
        __builtin_amdgcn_s_barrier();                                        \
        ++p;                                                                 \
    }

    for (int t = 0; t < 14; ++t) {
        PHASE(afA, bfA, afB, bfB, true, true, 4)     // p even
        PHASE(afB, bfB, afA, bfA, true, true, 4)     // p odd
    }
    PHASE(afA, bfA, afB, bfB, true,  true,  4)       // p=28 (stages kstep 31)
    PHASE(afB, bfB, afA, bfA, false, true,  0)       // p=29
    PHASE(afA, bfA, afB, bfB, false, true,  0)       // p=30
    PHASE(afB, bfB, afA, bfA, false, false, 0)       // p=31

#undef PHASE
#undef STG

    const int bb     = m0 >> 11;            // batch (uniform per wg)
    const int s_base = m0 & (SEQ - 1);

    if (n0 < 2048) {
        bf16* dst0 = (n0 < 1024) ? qb : kb;
        const int h = ((n0 + wc * 64) >> 6) & 15;
        const size_t bh = (size_t)(bb * NH + h);
        #pragma unroll
        for (int mi = 0; mi < 8; mi++) {
            const int s0 = s_base + wr * 128 + mi * 16 + quad * 4;
            #pragma unroll
            for (int ni = 0; ni < 4; ni++) {
                const int d = ni * 16 + l16;
                #pragma unroll
                for (int i = 0; i < 4; i++)
                    dst0[(bh * SEQ + s0 + i) * DH + d] = (bf16)acc[mi][ni][i];
            }
        }
    } else {
        __syncthreads();
        bf16* T = smem;                      // [256][256] bf16 = 128 KB
        #pragma unroll
        for (int ni = 0; ni < 4; ni++) {
            const int nl = wc * 64 + ni * 16 + l16;        // 0..255
            #pragma unroll
            for (int mi = 0; mi < 8; mi++) {
                const int ml = wr * 128 + mi * 16 + quad * 4;
                bf16x4 pv;
                #pragma unroll
                for (int i = 0; i < 4; i++) pv[i] = (bf16)acc[mi][ni][i];
                const int c   = ml >> 3;                    // 0..31
                const int swz = (c & 24) | ((c ^ nl) & 7);
                *(bf16x4*)&T[nl * 256 + swz * 8 + (ml & 7)] = pv;
            }
        }
        __syncthreads();
        const int hbase = (n0 - 2048) >> 6;
        #pragma unroll
        for (int it = 0; it < 8; it++) {
            const int nl = (tid >> 4) + it * 32;            // 0..255
            const int h  = hbase + (nl >> 6);
            const int d  = nl & 63;
            const size_t obase = ((size_t)(bb * NH + h) * DH + d) * SEQ + s_base;
            #pragma unroll
            for (int cc = 0; cc < 2; cc++) {
                const int c   = (tid & 15) + cc * 16;       // m-chunk 0..31
                const int swz = (c & 24) | ((c ^ nl) & 7);
                bf16x8 vv = *(const bf16x8*)&T[nl * 256 + swz * 8];
                *(bf16x8*)(vb + obase + c * 8) = vv;
            }
        }
    }
}

// ---------------------------------------------------------------------------
// Kernel 2: flash attention — R9-measured version, FROZEN (43.9 us, bank
// conflicts 65k). Extended swizzle slot = chunk ^ (row&7) ^ ((row>>3)&3).
// ---------------------------------------------------------------------------
__global__ __launch_bounds__(512, 4) void attn_kernel(
    const bf16* __restrict__ qb, const bf16* __restrict__ kb,
    const bf16* __restrict__ vb, bf16* __restrict__ ob)
{
    __shared__ __align__(16) bf16 smem[32768];   // 64 KB

    const int tid  = threadIdx.x;
    const int wave = tid >> 6;
    const int grp  = wave >> 2;        // key half
    const int wq   = wave & 3;         // q sub-block
    const int lane = tid & 63;
    const int l32  = lane & 31;
    const int hi   = lane >> 5;
    const int ltid = tid & 255;
    const int bh   = blockIdx.x;
    const int q0   = blockIdx.y * 128;
    const size_t base  = (size_t)bh * SEQ * DH;
    const int    kbase = grp * (SEQ / 2);

    bf16* const KsB = smem + grp * 2 * 4096;
    bf16* const VtB = smem + 16384 + grp * 2 * 4096;

    constexpr float QSCALE = 0.125f * 1.44269504f;

    bf16x8 qf[4];
    {
        const size_t qoff = base + (size_t)(q0 + wq * 32 + l32) * DH + hi * 8;
        #pragma unroll
        for (int kc = 0; kc < 4; kc++) {
            qf[kc] = *(const bf16x8*)(qb + qoff + kc * 16);
            #pragma unroll
            for (int j = 0; j < 8; j++)
                qf[kc][j] = (bf16)((float)qf[kc][j] * QSCALE);
        }
    }

    f32x16 o_acc[2];
    #pragma unroll
    for (int i = 0; i < 16; i++) { o_acc[0][i] = 0.f; o_acc[1][i] = 0.f; }
    float l_acc = 0.f;

    const int swz = (l32 & 7) ^ (l32 >> 3);

    const int so0 = ltid;
    const int so1 = 256 + ltid;
    const int sr0 = so0 >> 3, sc0 = ((so0 & 7) ^ (sr0 & 7) ^ ((sr0 >> 3) & 3)) * 8;
    const int sr1 = so1 >> 3, sc1 = ((so1 & 7) ^ (sr1 & 7) ^ ((sr1 >> 3) & 3)) * 8;

    #define STAGE(bufi, kk0)                                                   \
        do {                                                                   \
            gl_lds16(kb + base + (size_t)(kbase + (kk0) + sr0) * DH + sc0,     \
                     KsB + (bufi) * 4096 + so0 * 8);                           \
            gl_lds16(kb + base + (size_t)(kbase + (kk0) + sr1) * DH + sc1,     \
                     KsB + (bufi) * 4096 + so1 * 8);                           \
            gl_lds16(vb + base + (size_t)sr0 * SEQ + kbase + (kk0) + sc0,      \
                     VtB + (bufi) * 4096 + so0 * 8);                           \
            gl_lds16(vb + base + (size_t)sr1 * SEQ + kbase + (kk0) + sc1,      \
                     VtB + (bufi) * 4096 + so1 * 8);                           \
        } while (0)

    STAGE(0, 0);
    int buf = 0;

    for (int kt = 0; kt < SEQ / 128; ++kt) {
        __syncthreads();
        if (kt + 1 < SEQ / 128) STAGE(buf ^ 1, (kt + 1) * 64);

        const bf16* Kst = KsB + buf * 4096;
        const bf16* Vtt = VtB + buf * 4096;

        #pragma unroll
        for (int kblk = 0; kblk < 2; kblk++) {
            f32x16 sacc;
            #pragma unroll
            for (int i = 0; i < 16; i++) sacc[i] = 0.f;
            #pragma unroll
            for (int kc = 0; kc < 4; kc++) {
                const int cko = ((2 * kc + hi) ^ swz) * 8;
                bf16x8 kf = *(const bf16x8*)
                    &Kst[(kblk * 32 + l32) * 64 + cko];
                sacc = MFMA32(kf, qf[kc], sacc);
            }

            int w[8];
            #pragma unroll
            for (int c = 0; c < 8; c++) {
                const float e0 = __builtin_amdgcn_exp2f(sacc[2 * c]);
                const float e1 = __builtin_amdgcn_exp2f(sacc[2 * c + 1]);
                l_acc += e0;
                l_acc += e1;
                bf16x2 t; t[0] = (bf16)e0; t[1] = (bf16)e1;
                w[c] = __builtin_bit_cast(int, t);
            }
            #pragma unroll
            for (int cc = 0; cc < 2; cc++) {
                pl32swap(w[cc * 4 + 0], w[cc * 4 + 2]);
                pl32swap(w[cc * 4 + 1], w[cc * 4 + 3]);
                i32x4 fi = {w[cc * 4 + 0], w[cc * 4 + 1],
                            w[cc * 4 + 2], w[cc * 4 + 3]};
                bf16x8 pa = __builtin_bit_cast(bf16x8, fi);

                const int kc = kblk * 2 + cc;
                const int cko = ((2 * kc + hi) ^ swz) * 8;
                #pragma unroll
                for (int nb = 0; nb < 2; nb++) {
                    bf16x8 vf = *(const bf16x8*)
                        &Vtt[(nb * 32 + l32) * 64 + cko];
                    o_acc[nb] = MFMA32(pa, vf, o_acc[nb]);
                }
            }
        }
        buf ^= 1;
    }
    #undef STAGE

    const float l_q = l_acc + __shfl_xor(l_acc, 32);

    float* cO  = (float*)smem;            // [4][64][32] f32, swizzled
    float* cL1 = (float*)smem + 8192;     // [4][32] : grp1 partial l
    float* cL2 = (float*)smem + 8320;     // [4][32] : total l

    __syncthreads();                      // everyone done with Ks/Vt
    if (grp == 1) {
        #pragma unroll
        for (int nb = 0; nb < 2; nb++)
            #pragma unroll
            for (int c4 = 0; c4 < 4; c4++) {
                const int j = nb * 4 + c4;
                f32x4 v = { o_acc[nb][c4 * 4 + 0], o_acc[nb][c4 * 4 + 1],
                            o_acc[nb][c4 * 4 + 2], o_acc[nb][c4 * 4 + 3] };
                *(f32x4*)&cO[(wq * 64 + lane) * 32 + ((j ^ (lane & 7)) * 4)] = v;
            }
        if (hi == 0) cL1[wq * 32 + l32] = l_q;
    }
    __syncthreads();
    if (grp == 0) {
        #pragma unroll
        for (int nb = 0; nb < 2; nb++)
            #pragma unroll
            for (int c4 = 0; c4 < 4; c4++) {
                const int j = nb * 4 + c4;
                f32x4 v = *(const f32x4*)
                    &cO[(wq * 64 + lane) * 32 + ((j ^ (lane & 7)) * 4)];
                #pragma unroll
                for (int e = 0; e < 4; e++) o_acc[nb][c4 * 4 + e] += v[e];
            }
        if (hi == 0) cL2[wq * 32 + l32] = l_q + cL1[wq * 32 + l32];
    }
    __syncthreads();
    if (grp == 0) {
        const int b = bh >> 4, h = bh & 15;
        #pragma unroll
        for (int i = 0; i < 16; i++) {
            const int qrow = (i & 3) + 8 * (i >> 2) + 4 * hi;
            const int q = q0 + wq * 32 + qrow;
            const float li = 1.0f / cL2[wq * 32 + qrow];
            #pragma unroll
            for (int nb = 0; nb < 2; nb++)
                ob[((size_t)(b * SEQ + q) * NH + h) * DH + nb * 32 + l32] =
                    (bf16)(o_acc[nb][i] * li);
        }
    }
}

// ---------------------------------------------------------------------------
// Kernel 3: out = attn @ Wout^T — NEW: R5-style ping-pong one-barrier
// pipeline (ring-of-4 K=32 slabs, reads of slab p+1 interleaved between MFMA
// clusters of slab p, stage targets slab (p+3)%4, counted vmcnt(4), no lgkm
// drain). 128x128 tile, 256 threads, 4 waves (2x2), 64 KB LDS.
// ---------------------------------------------------------------------------
__global__ __launch_bounds__(256, 2) void out_gemm_kernel(
    const bf16* __restrict__ A, const bf16* __restrict__ Wt,
    float* __restrict__ out)
{
    __shared__ __align__(16) bf16 smem[32768];   // 64 KB
    bf16* const sA = smem;                        // 4 x 4096 elems
    bf16* const sB = smem + 16384;                // 4 x 4096 elems

    const int tid  = threadIdx.x;
    const int wave = tid >> 6;
    const int lane = tid & 63;
    const int quad = lane >> 4;
    const int l16  = lane & 15;
    const int wr   = wave >> 1;        // 0..1 : A row half
    const int wc   = wave & 1;         // 0..1 : B col half
    const int m0   = blockIdx.x * 128;
    const int n0   = blockIdx.y * 128;

    const int sr2  = tid >> 3;                   // super-row 0..31
    const int c8p  = (tid & 7) ^ (sr2 & 7);
    const int stR0 = (sr2 << 1) | (c8p >> 2);    // row 0..63 (slot1: +64)
    const int stC0 = (c8p & 3) << 3;

    const bf16* Asrc = A  + (size_t)(m0 + stR0) * D_MODEL + stC0;
    const bf16* Bsrc = Wt + (size_t)(n0 + stR0) * D_MODEL + stC0;

#define STG(s, kbo)                                                          \
    do {                                                                     \
        gl_lds16(Asrc + (kbo),                sA + (s) * 4096 + tid * 8);    \
        gl_lds16(Asrc + 64 * D_MODEL + (kbo), sA + (s) * 4096 + 2048 + tid * 8); \
        gl_lds16(Bsrc + (kbo),                sB + (s) * 4096 + tid * 8);    \
        gl_lds16(Bsrc + 64 * D_MODEL + (kbo), sB + (s) * 4096 + 2048 + tid * 8); \
    } while (0)

    const int foff = ((l16 >> 1) << 6) +
                     (((((l16 & 1) << 2) | quad) ^ ((l16 >> 1) & 7)) << 3);

    f32x4 acc[4][4];
    #pragma unroll
    for (int a = 0; a < 4; a++)
        #pragma unroll
        for (int b = 0; b < 4; b++) acc[a][b] = {0.f, 0.f, 0.f, 0.f};

    bf16x8 afA[4], bfA[4], afB[4], bfB[4];

    // prologue: stage ksteps 0..2; certify 0,1 landed; read kstep 0 -> bank A
    STG(0, 0); STG(1, 32); STG(2, 64);
    waitv<4>();
    __builtin_amdgcn_s_barrier();
    {
        const bf16* A0 = sA + wr * 2048;
        const bf16* B0 = sB + wc * 2048;
        #pragma unroll
        for (int mi = 0; mi < 4; mi++)
            afA[mi] = *(const bf16x8*)&A0[mi * 512 + foff];
        #pragma unroll
        for (int ni = 0; ni < 4; ni++)
            bfA[ni] = *(const bf16x8*)&B0[ni * 512 + foff];
    }

    int p = 0;

#define PHASE(CA, CB, NA, NB, DOSTG, DONXT, WV)                              \
    {                                                                        \
        if (DOSTG) { const int kst = p + 3; STG((kst & 3), kst * 32); }      \
        const int sn = (p + 1) & 3;                                          \
        const bf16* An_ = sA + sn * 4096 + wr * 2048;                        \
        const bf16* Bn_ = sB + sn * 4096 + wc * 2048;                        \
        __builtin_amdgcn_s_setprio(1);                                       \
        _Pragma("unroll") for (int mi = 0; mi < 4; mi++) {                   \
            _Pragma("unroll") for (int ni = 0; ni < 4; ni++)                 \
                acc[mi][ni] = MFMA16(CA[mi], CB[ni], acc[mi][ni]);           \
            if (DONXT) NA[mi] = *(const bf16x8*)&An_[mi * 512 + foff];       \
        }                                                                    \
        if (DONXT) {                                                         \
            _Pragma("unroll") for (int ni = 0; ni < 4; ni++)                 \
                NB[ni] = *(const bf16x8*)&Bn_[ni * 512 + foff];              \
        }                                                                    \
        __builtin_amdgcn_s_setprio(0);                                       \
        waitv<WV>();                                                         \
        __builtin_amdgcn_s_barrier();                                        \
        ++p;                                                                 \
    }

    for (int t = 0; t < 14; ++t) {
        PHASE(afA, bfA, afB, bfB, true, true, 4)     // p even
        PHASE(afB, bfB, afA, bfA, true, true, 4)     // p odd
    }
    PHASE(afA, bfA, afB, bfB, true,  true,  4)       // p=28 (stages kstep 31)
    PHASE(afB, bfB, afA, bfA, false, true,  0)       // p=29
    PHASE(afA, bfA, afB, bfB, false, true,  0)       // p=30
    PHASE(afB, bfB, afA, bfA, false, false, 0)       // p=31

#undef PHASE
#undef STG

    #pragma unroll
    for (int mi = 0; mi < 4; mi++) {
        const int row0 = m0 + wr * 64 + mi * 16 + quad * 4;
        #pragma unroll
        for (int ni = 0; ni < 4; ni++) {
            const int n = n0 + wc * 64 + ni * 16 + l16;
            #pragma unroll
            for (int i = 0; i < 4; i++)
                out[(size_t)(row0 + i) * D_MODEL + n] = acc[mi][ni][i];
        }
    }
}

// ---------------------------------------------------------------------------
extern "C" void kernel_launch(void* const* d_in, const int* in_sizes, int n_in,
                              void* d_out, int out_size, void* d_ws, size_t ws_size,
                              hipStream_t stream)
{
    const float* X    = (const float*)d_in[0];
    const float* Wqkv = (const float*)d_in[1];
    const float* Wout = (const float*)d_in[2];
    float* out        = (float*)d_out;

    const size_t n_elem = (size_t)M_TOT * D_MODEL;       // 4096*1024
    bf16* qb      = (bf16*)d_ws;
    bf16* kb      = qb + n_elem;
    bf16* vb      = kb + n_elem;
    bf16* attnb   = vb + n_elem;
    bf16* wqkv_t  = attnb + n_elem;                      // 3072*1024
    bf16* wout_t  = wqkv_t + (size_t)N_QKV * D_MODEL;    // 1024*1024
    bf16* xb      = wout_t + (size_t)D_MODEL * D_MODEL;  // 4096*1024

    prepass_kernel<<<3072, 256, 0, stream>>>(X, Wqkv, Wout, xb, wqkv_t, wout_t);

    qkv_gemm_kernel<<<dim3(M_TOT / 256, N_QKV / 256), 512, 0, stream>>>(
        xb, wqkv_t, qb, kb, vb);
    attn_kernel<<<dim3(BATCH * NH, SEQ / 128), 512, 0, stream>>>(qb, kb, vb, attnb);
    out_gemm_kernel<<<dim3(M_TOT / 128, D_MODEL / 128), 256, 0, stream>>>(
        attnb, wout_t, out);
}